// Round 1
// baseline (171.530 us; speedup 1.0000x reference)
//
#include <hip/hip_runtime.h>

// Detail_loss: loss = 0.25/(98*258*256) * sum_{n,h,w} ( |D[h][w+1]-D[h][w-1]| + |D[h+1][w]-D[h-1][w]| )
// where D[n,h,w] = sum_c (infer - ref)[n,c,h,w], zero outside [0,256)^2.
//
// R6: R5's global_load_lds + barrier-drain structure is structurally serialized:
// L3-resident replays (hbm_bytes ~100 KB) take the SAME 54us as HBM-fed runs, so
// the kernel is not bandwidth-bound — it's stalled in the vmcnt(0) drain the
// compiler emits before every __syncthreads, with only ~1 effective block/CU
// (72 KB LDS, OccupancyPercent 14%). The 3-row stencil never needed LDS at all.
// New structure: pure register streaming. 1 wave = 1 band (8 output rows), lane
// owns 4 columns (float4 loads, 1 KB/wave-instr coalesced). D rows live in a
// 3-row sliding register window; vertical term is register-local; horizontal
// term is 2 shuffles/row. Zero LDS, zero barriers -> loads for row r+2 stay in
// flight while row r computes, and 12-16 resident waves/CU give Little's-law
// headroom (need only ~9 KB/CU in flight for 6.3 TB/s).

#define W 256
#define NIMG 98
#define CH_STRIDE 65536          // 256*256 floats per channel
#define TH 8                     // output rows per band
#define NSTRIP 32                // 256 / TH
#define NBLK (NIMG * NSTRIP)     // 3136 bands = 3136 one-wave blocks
#define SCALE (0.25f / 6472704.0f)   // 0.25/(98*258*256)

struct Row6 { float4 a0, a1, a2, b0, b1, b2; };

__device__ __forceinline__ int clampg(int g) {
  return g < 0 ? 0 : (g > 255 ? 255 : g);
}

// Issue the 6 float4 loads for one (clamped) image row. Loads are independent
// of all compute; caller keeps the Row6 live so they stay in flight.
__device__ __forceinline__ Row6 issue_row(const float* __restrict__ xb,
                                          const float* __restrict__ yb,
                                          int g) {
  const int ro = g * W;          // float offset of the row (lane offset folded into xb/yb)
  Row6 r;
  r.a0 = *(const float4*)(xb + ro);
  r.a1 = *(const float4*)(xb + ro + CH_STRIDE);
  r.a2 = *(const float4*)(xb + ro + 2 * CH_STRIDE);
  r.b0 = *(const float4*)(yb + ro);
  r.b1 = *(const float4*)(yb + ro + CH_STRIDE);
  r.b2 = *(const float4*)(yb + ro + 2 * CH_STRIDE);
  return r;
}

// Channel-summed difference row, masked to 0 for padding rows (mask is
// wave-uniform 0.f/1.f; clamped OOB loads read valid finite data, then *0).
__device__ __forceinline__ float4 combine(const Row6& r, float m) {
  float4 d;
  d.x = m * ((r.a0.x - r.b0.x) + (r.a1.x - r.b1.x) + (r.a2.x - r.b2.x));
  d.y = m * ((r.a0.y - r.b0.y) + (r.a1.y - r.b1.y) + (r.a2.y - r.b2.y));
  d.z = m * ((r.a0.z - r.b0.z) + (r.a1.z - r.b1.z) + (r.a2.z - r.b2.z));
  d.w = m * ((r.a0.w - r.b0.w) + (r.a1.w - r.b1.w) + (r.a2.w - r.b2.w));
  return d;
}

__device__ __forceinline__ float band_body(const float* __restrict__ x,
                                           const float* __restrict__ y) {
  const int lane  = threadIdx.x;   // 0..63, one wave per block
  const int b     = blockIdx.x;
  const int n     = b >> 5;        // image
  const int strip = b & 31;
  const int r0    = strip * TH;

  const float* xb = x + (size_t)n * 3 * CH_STRIDE + (lane << 2);
  const float* yb = y + (size_t)n * 3 * CH_STRIDE + (lane << 2);

  // Prologue: rows r0-1, r0, r0+1 issued back-to-back (18 loads in flight).
  Row6 s0 = issue_row(xb, yb, clampg(r0 - 1));
  Row6 s1 = issue_row(xb, yb, r0);
  Row6 pend = issue_row(xb, yb, r0 + 1);

  float4 dprev = combine(s0, (r0 - 1 >= 0) ? 1.f : 0.f);
  float4 dcur  = combine(s1, 1.f);

  float acc = 0.f;
  #pragma unroll
  for (int r = 0; r < TH; ++r) {
    // Issue row r0+r+2 two iterations ahead of its use; final (overshoot) issue
    // is never combined -> dead-code eliminated.
    Row6 nxt = issue_row(xb, yb, clampg(r0 + r + 2));
    float4 dnext = combine(pend, (r0 + r + 1 <= 255) ? 1.f : 0.f);

    // Horizontal: |D[w+1]-D[w-1]| for this lane's 4 columns of row r0+r.
    float lm = __shfl_up(dcur.w, 1);    // left neighbor's col 4L-1
    if (lane == 0) lm = 0.f;            // image col -1 zero pad
    float rp = __shfl_down(dcur.x, 1);  // right neighbor's col 4L+4
    if (lane == 63) rp = 0.f;           // image col 256 zero pad
    acc += fabsf(dcur.y - lm) + fabsf(dcur.z - dcur.x)
         + fabsf(dcur.w - dcur.y) + fabsf(rp - dcur.z);

    // Vertical: |D[h+1]-D[h-1]|, all register-local.
    acc += fabsf(dnext.x - dprev.x) + fabsf(dnext.y - dprev.y)
         + fabsf(dnext.z - dprev.z) + fabsf(dnext.w - dprev.w);

    dprev = dcur; dcur = dnext; pend = nxt;
  }

  // Wave reduce (block == 1 wave; no LDS, no barrier).
  #pragma unroll
  for (int off = 32; off > 0; off >>= 1)
    acc += __shfl_down(acc, off, 64);
  return acc;
}

__global__ __launch_bounds__(64) void detail_stage1(
    const float* __restrict__ x, const float* __restrict__ y,
    float* __restrict__ partial) {
  float s = band_body(x, y);
  if (threadIdx.x == 0) partial[blockIdx.x] = s;
}

__global__ __launch_bounds__(64) void detail_stage1_atomic(
    const float* __restrict__ x, const float* __restrict__ y,
    float* __restrict__ out) {
  float s = band_body(x, y);
  if (threadIdx.x == 0) atomicAdd(out, s * SCALE);
}

__global__ __launch_bounds__(256) void detail_stage2(
    const float* __restrict__ partial, float* __restrict__ out) {
  float acc = 0.f;
  for (int i = threadIdx.x; i < NBLK; i += 256) acc += partial[i];
  #pragma unroll
  for (int off = 32; off > 0; off >>= 1)
    acc += __shfl_down(acc, off, 64);
  __shared__ float ws[4];
  if ((threadIdx.x & 63) == 0) ws[threadIdx.x >> 6] = acc;
  __syncthreads();
  if (threadIdx.x == 0) out[0] = (ws[0] + ws[1] + ws[2] + ws[3]) * SCALE;
}

extern "C" void kernel_launch(void* const* d_in, const int* in_sizes, int n_in,
                              void* d_out, int out_size, void* d_ws, size_t ws_size,
                              hipStream_t stream) {
  const float* infer = (const float*)d_in[0];
  const float* ref   = (const float*)d_in[1];
  float* out = (float*)d_out;

  if (ws_size >= NBLK * sizeof(float)) {
    float* partial = (float*)d_ws;
    detail_stage1<<<NBLK, 64, 0, stream>>>(infer, ref, partial);
    detail_stage2<<<1, 256, 0, stream>>>(partial, out);
  } else {
    hipMemsetAsync(out, 0, sizeof(float), stream);
    detail_stage1_atomic<<<NBLK, 64, 0, stream>>>(infer, ref, out);
  }
}